// Round 8
// baseline (332.182 us; speedup 1.0000x reference)
//
#include <hip/hip_runtime.h>
#include <cmath>

// ============================================================================
// SpatialContextSet — round 8.
// vs r7: (1) EXACT attention/Wo algebra: the r3-r7 W2o fold applied the head
// weighting to the wrong index (masked by tolerance). Now: P6 computes
// vtok = t1@W2 (swapped), contracts tokens in-register with watt[w][t]
// (m's head == wave), reduces over l16 lanes, then M=1 zflat@Wo GEMM.
// (2) W2o fold + prep2 deleted -> 3 dispatches (prep, pre, fused).
// ============================================================================

typedef __bf16 bf16;
typedef bf16 bf16x4 __attribute__((ext_vector_type(4)));
typedef bf16 bf16x8 __attribute__((ext_vector_type(8)));
typedef float f32x4 __attribute__((ext_vector_type(4)));

#define MFMA_B16(a, b, c) __builtin_amdgcn_mfma_f32_16x16x32_bf16((a), (b), (c), 0, 0, 0)
#define RCP(x) __builtin_amdgcn_rcpf(x)
#define RSQ(x) __builtin_amdgcn_rsqf(x)

constexpr int SROW = 264;  // LDS buf row stride bf16 (528 B)
constexpr int XROW = 72;   // x staging row stride bf16 (144 B)

// ---- workspace layout (bf16 element offsets) ----
constexpr size_t WSTAT_P = 0;          // 4w*2ks*2048 = 16384
constexpr size_t WV_P    = 16384;      // 65536
constexpr size_t W1_P    = 81920;      // 65536
constexpr size_t W2_P    = 147456;     // 65536
constexpr size_t WO_P    = 212992;     // 65536
constexpr size_t WDYN_P  = 278528;     // 131072
constexpr size_t WQ_P    = 409600;     // 65536
constexpr size_t WK_P    = 475136;     // 65536 (trans-packed)
constexpr size_t KQ_BF   = 540672;     // [4096][4][256] -> ends 4734976
// float element offsets (from (float*)ws):
constexpr size_t H0_F  = 2367488;      // [4096][256]
constexpr size_t BKQ_F = 3416064;      // [4096][4]

__device__ __forceinline__ bf16x8 zero8() {
  bf16x8 z;
#pragma unroll
  for (int j = 0; j < 8; ++j) z[j] = (bf16)0.0f;
  return z;
}

__device__ __forceinline__ float wave_sum(float v) {
#pragma unroll
  for (int m = 1; m < 64; m <<= 1) v += __shfl_xor(v, m, 64);
  return v;
}

__device__ __forceinline__ void zero_acc(f32x4 (&acc)[4][4]) {
#pragma unroll
  for (int mt = 0; mt < 4; ++mt)
#pragma unroll
    for (int nt = 0; nt < 4; ++nt) { f32x4 z = {0.f, 0.f, 0.f, 0.f}; acc[mt][nt] = z; }
}

// ---- packed swapped GEMM (K=256): A=packed W frags (global), B=buf rows (LDS)
// acc[dt][tt] -> (dim = w*64+dt*16+quad*4+r, token = tt*16+l16)
__device__ __forceinline__ void gemm_swapped_p(const bf16* buf, const bf16* __restrict__ Wp,
                                               int w, int lane, int l16, int koff,
                                               f32x4 (&acc)[4][4]) {
  const bf16* base = Wp + (size_t)w * 8 * 2048 + lane * 8;
  bf16x8 aw[2][4];
#pragma unroll
  for (int dt = 0; dt < 4; ++dt) aw[0][dt] = *(const bf16x8*)(base + dt * 512);
#pragma unroll
  for (int ks = 0; ks < 8; ++ks) {
    const int cur = ks & 1;
    if (ks < 7) {
#pragma unroll
      for (int dt = 0; dt < 4; ++dt)
        aw[cur ^ 1][dt] = *(const bf16x8*)(base + (ks + 1) * 2048 + dt * 512);
    }
#pragma unroll
    for (int tt = 0; tt < 4; ++tt) {
      bf16x8 bfrag = *(const bf16x8*)(buf + (tt * 16 + l16) * SROW + ks * 32 + koff);
#pragma unroll
      for (int dt = 0; dt < 4; ++dt) acc[dt][tt] = MFMA_B16(aw[cur][dt], bfrag, acc[dt][tt]);
    }
  }
}

// ---- add bias into acc + per-token LN partials -> LDS (values stay in regs)
__device__ __forceinline__ void bias_stats(f32x4 (&acc)[4][4], const float* __restrict__ bsrc,
                                           int w, int quad, int l16,
                                           float (*part_s)[64], float (*part_ss)[64]) {
  float ps[4] = {0.f, 0.f, 0.f, 0.f}, pq[4] = {0.f, 0.f, 0.f, 0.f};
#pragma unroll
  for (int dt = 0; dt < 4; ++dt) {
    const float4 bb = *(const float4*)(bsrc + w * 64 + dt * 16 + quad * 4);
#pragma unroll
    for (int tt = 0; tt < 4; ++tt) {
      float v0 = acc[dt][tt][0] + bb.x;
      float v1 = acc[dt][tt][1] + bb.y;
      float v2 = acc[dt][tt][2] + bb.z;
      float v3 = acc[dt][tt][3] + bb.w;
      acc[dt][tt][0] = v0; acc[dt][tt][1] = v1; acc[dt][tt][2] = v2; acc[dt][tt][3] = v3;
      ps[tt] += (v0 + v1) + (v2 + v3);
      pq[tt] += v0 * v0 + v1 * v1 + v2 * v2 + v3 * v3;
    }
  }
#pragma unroll
  for (int tt = 0; tt < 4; ++tt) {
    ps[tt] += __shfl_xor(ps[tt], 16, 64); ps[tt] += __shfl_xor(ps[tt], 32, 64);
    pq[tt] += __shfl_xor(pq[tt], 16, 64); pq[tt] += __shfl_xor(pq[tt], 32, 64);
  }
  if (quad == 0) {
#pragma unroll
    for (int tt = 0; tt < 4; ++tt) {
      part_s[w][tt * 16 + l16] = ps[tt];
      part_ss[w][tt * 16 + l16] = pq[tt];
    }
  }
}

// ---- after barrier: finalize LN stats, apply to register values, store bf16
__device__ __forceinline__ void ln_apply_store(f32x4 (&acc)[4][4], const float* __restrict__ g,
                                               const float* __restrict__ bsh, bf16* buf,
                                               const float (*part_s)[64],
                                               const float (*part_ss)[64],
                                               int w, int quad, int l16) {
  float mean[4], rstd[4];
#pragma unroll
  for (int tt = 0; tt < 4; ++tt) {
    const int tok = tt * 16 + l16;
    float s = (part_s[0][tok] + part_s[1][tok]) + (part_s[2][tok] + part_s[3][tok]);
    float q = (part_ss[0][tok] + part_ss[1][tok]) + (part_ss[2][tok] + part_ss[3][tok]);
    mean[tt] = s * (1.f / 256.f);
    float var = q * (1.f / 256.f) - mean[tt] * mean[tt];
    rstd[tt] = RSQ(var + 1e-5f);
  }
#pragma unroll
  for (int dt = 0; dt < 4; ++dt) {
    const float4 gv = *(const float4*)(g + w * 64 + dt * 16 + quad * 4);
    const float4 bv = *(const float4*)(bsh + w * 64 + dt * 16 + quad * 4);
#pragma unroll
    for (int tt = 0; tt < 4; ++tt) {
      float t0 = (acc[dt][tt][0] - mean[tt]) * rstd[tt];
      float t1 = (acc[dt][tt][1] - mean[tt]) * rstd[tt];
      float t2 = (acc[dt][tt][2] - mean[tt]) * rstd[tt];
      float t3 = (acc[dt][tt][3] - mean[tt]) * rstd[tt];
      bf16x4 o;
      o[0] = (bf16)(t0 * gv.x + bv.x);
      o[1] = (bf16)(t1 * gv.y + bv.y);
      o[2] = (bf16)(t2 * gv.z + bv.z);
      o[3] = (bf16)(t3 * gv.w + bv.w);
      *(bf16x4*)(buf + (tt * 16 + l16) * SROW + w * 64 + dt * 16 + quad * 4) = o;
    }
  }
}

// ---- fragment packer (one (w,ks) slice -> 2048 bf16)
__device__ __forceinline__ void pack_slice(const float* __restrict__ src, bf16* __restrict__ dstb,
                                           int w, int ks, bool trans, float* sh, int tid) {
  if (!trans) {
#pragma unroll
    for (int i = 0; i < 8; ++i) {
      int r = i * 4 + (tid >> 6), c = tid & 63;
      sh[r * 65 + c] = src[(size_t)(ks * 32 + r) * 256 + w * 64 + c];
    }
  } else {
    int c = tid >> 2, j8 = tid & 3;
#pragma unroll
    for (int jj = 0; jj < 8; ++jj) {
      int r = j8 * 8 + jj;
      sh[r * 65 + c] = src[(size_t)(w * 64 + c) * 256 + ks * 32 + r];
    }
  }
  __syncthreads();
  const int x = tid >> 6, quad = (tid >> 4) & 3, l16 = tid & 15;
  bf16x8 o;
#pragma unroll
  for (int j = 0; j < 8; ++j) o[j] = (bf16)sh[(quad * 8 + j) * 65 + x * 16 + l16];
  *(bf16x8*)(dstb + tid * 8) = o;
}

// ---------------------------------------------------------------------------
// prep: 264 blocks, pure fragment packing (W2/Wo packed directly; no fold)
// ---------------------------------------------------------------------------
__global__ void prep_kernel(const float* __restrict__ Wdyn, const float* __restrict__ Wstat,
                            const float* __restrict__ Wq, const float* __restrict__ Wk,
                            const float* __restrict__ Wv, const float* __restrict__ W1,
                            const float* __restrict__ W2, const float* __restrict__ Wo,
                            bf16* __restrict__ ws) {
  __shared__ float sh[64 * 65];
  int t = blockIdx.x;
  const float* src; bf16* dst; int KS; bool trans = false;
  if (t < 64)       { src = Wdyn;  dst = ws + WDYN_P;  KS = 16; }
  else if (t < 72)  { src = Wstat; dst = ws + WSTAT_P; KS = 2;  t -= 64; }
  else if (t < 104) { src = Wq;    dst = ws + WQ_P;    KS = 8;  t -= 72; }
  else if (t < 136) { src = Wv;    dst = ws + WV_P;    KS = 8;  t -= 104; }
  else if (t < 168) { src = W1;    dst = ws + W1_P;    KS = 8;  t -= 136; }
  else if (t < 200) { src = W2;    dst = ws + W2_P;    KS = 8;  t -= 168; }
  else if (t < 232) { src = Wo;    dst = ws + WO_P;    KS = 8;  t -= 200; }
  else              { src = Wk;    dst = ws + WK_P;    KS = 8;  t -= 232; trans = true; }
  const int w = t / KS, ks = t % KS;
  pack_slice(src, dst + (size_t)(w * KS + ks) * 2048, w, ks, trans, sh, threadIdx.x);
}

// ---------------------------------------------------------------------------
// pre: grid 512, 8 batch rows per WG. GEMMs register-double-buffered.
// ---------------------------------------------------------------------------
__launch_bounds__(256, 2)
__global__ void pre_kernel(const float* __restrict__ h_dyn, const float* __restrict__ b_dyn,
                           const float* __restrict__ g_ndyn, const float* __restrict__ b_ndyn,
                           const float* __restrict__ bq, const float* __restrict__ bk,
                           const bf16* __restrict__ Wdyn_p, const bf16* __restrict__ Wq_p,
                           const bf16* __restrict__ Wk_p,
                           float* __restrict__ h0_out, bf16* __restrict__ kq_out,
                           float* __restrict__ bkq_out) {
  __shared__ float h0t[8][264];
  __shared__ bf16 hlnt[8][264];
  __shared__ bf16 qt[8][264];
  const int tid = threadIdx.x;
  const int w = tid >> 6, lane = tid & 63, quad = lane >> 4, l16 = lane & 15;
  const int koff = quad * 8;
  const int b0 = blockIdx.x * 8;
  const int mrow = l16 & 7;

  // h0 (K=512), dbuf weights
  {
    f32x4 acc[4];
#pragma unroll
    for (int nt = 0; nt < 4; ++nt) { f32x4 z = {0.f, 0.f, 0.f, 0.f}; acc[nt] = z; }
    const float* arow = h_dyn + (size_t)(b0 + mrow) * 512;
    const bf16* base = Wdyn_p + (size_t)w * 16 * 2048 + lane * 8;
    bf16x8 bw[2][4];
#pragma unroll
    for (int nt = 0; nt < 4; ++nt) bw[0][nt] = *(const bf16x8*)(base + nt * 512);
    for (int ks = 0; ks < 16; ++ks) {
      const int cur = ks & 1;
      if (ks < 15) {
#pragma unroll
        for (int nt = 0; nt < 4; ++nt)
          bw[cur ^ 1][nt] = *(const bf16x8*)(base + (ks + 1) * 2048 + nt * 512);
      }
      float4 x0 = *(const float4*)(arow + ks * 32 + koff);
      float4 x1 = *(const float4*)(arow + ks * 32 + koff + 4);
      bf16x8 a;
      a[0] = (bf16)x0.x; a[1] = (bf16)x0.y; a[2] = (bf16)x0.z; a[3] = (bf16)x0.w;
      a[4] = (bf16)x1.x; a[5] = (bf16)x1.y; a[6] = (bf16)x1.z; a[7] = (bf16)x1.w;
#pragma unroll
      for (int nt = 0; nt < 4; ++nt) acc[nt] = MFMA_B16(a, bw[cur][nt], acc[nt]);
    }
    if (quad < 2) {
#pragma unroll
      for (int nt = 0; nt < 4; ++nt) {
        int col = w * 64 + nt * 16 + l16;
        float bb = b_dyn[col];
#pragma unroll
        for (int r = 0; r < 4; ++r) {
          int row = quad * 4 + r;
          float v = acc[nt][r] + bb;
          h0t[row][col] = v;
          h0_out[(size_t)(b0 + row) * 256 + col] = v;
        }
      }
    }
  }
  __syncthreads();

  // LN over 8 rows
  {
    float gn[4], bn[4];
#pragma unroll
    for (int j = 0; j < 4; ++j) { gn[j] = g_ndyn[lane + 64 * j]; bn[j] = b_ndyn[lane + 64 * j]; }
#pragma unroll
    for (int i = 0; i < 2; ++i) {
      int row = 4 * i + w;
      float x[4]; float s = 0.f, ss = 0.f;
#pragma unroll
      for (int j = 0; j < 4; ++j) { x[j] = h0t[row][lane + 64 * j]; s += x[j]; ss += x[j] * x[j]; }
      s = wave_sum(s); ss = wave_sum(ss);
      float mean = s * (1.f / 256.f);
      float var = ss * (1.f / 256.f) - mean * mean;
      float rstd = RSQ(var + 1e-5f);
#pragma unroll
      for (int j = 0; j < 4; ++j)
        hlnt[row][lane + 64 * j] = (bf16)((x[j] - mean) * rstd * gn[j] + bn[j]);
    }
  }
  __syncthreads();

  // q = hln@Wq + bq (dbuf)
  {
    f32x4 acc[4];
#pragma unroll
    for (int nt = 0; nt < 4; ++nt) { f32x4 z = {0.f, 0.f, 0.f, 0.f}; acc[nt] = z; }
    const bf16* base = Wq_p + (size_t)w * 8 * 2048 + lane * 8;
    bf16x8 bw[2][4];
#pragma unroll
    for (int nt = 0; nt < 4; ++nt) bw[0][nt] = *(const bf16x8*)(base + nt * 512);
    for (int ks = 0; ks < 8; ++ks) {
      const int cur = ks & 1;
      if (ks < 7) {
#pragma unroll
        for (int nt = 0; nt < 4; ++nt)
          bw[cur ^ 1][nt] = *(const bf16x8*)(base + (ks + 1) * 2048 + nt * 512);
      }
      bf16x8 a = *(const bf16x8*)(&hlnt[mrow][ks * 32 + koff]);
#pragma unroll
      for (int nt = 0; nt < 4; ++nt) acc[nt] = MFMA_B16(a, bw[cur][nt], acc[nt]);
    }
    if (quad < 2) {
#pragma unroll
      for (int nt = 0; nt < 4; ++nt) {
        int col = w * 64 + nt * 16 + l16;
        float bb = bq[col];
#pragma unroll
        for (int r = 0; r < 4; ++r)
          qt[quad * 4 + r][col] = (bf16)(acc[nt][r] + bb);
      }
    }
  }
  __syncthreads();

  // bkq[b,h] = bk_h . q_h
  {
    const int pair = tid >> 2;
    const int row = pair >> 2, h = pair & 3, sub = tid & 3;
    if (row < 8) {
      float p = 0.f;
#pragma unroll
      for (int j = 0; j < 16; ++j) {
        int e = sub * 16 + j;
        p += (float)qt[row][h * 64 + e] * bk[h * 64 + e];
      }
      p += __shfl_xor(p, 1, 64);
      p += __shfl_xor(p, 2, 64);
      if (sub == 0) bkq_out[(size_t)(b0 + row) * 4 + h] = p;
    }
  }

  // kq per head
  for (int h = 0; h < 4; ++h) {
    f32x4 acc[4];
#pragma unroll
    for (int nt = 0; nt < 4; ++nt) { f32x4 z = {0.f, 0.f, 0.f, 0.f}; acc[nt] = z; }
    const bf16* base = Wk_p + (size_t)w * 8 * 2048 + lane * 8;
#pragma unroll
    for (int ks = 0; ks < 2; ++ks) {
      bf16x8 a = *(const bf16x8*)(&qt[mrow][h * 64 + ks * 32 + koff]);
#pragma unroll
      for (int nt = 0; nt < 4; ++nt) {
        bf16x8 bw = *(const bf16x8*)(base + (h * 2 + ks) * 2048 + nt * 512);
        acc[nt] = MFMA_B16(a, bw, acc[nt]);
      }
    }
    if (quad < 2) {
#pragma unroll
      for (int nt = 0; nt < 4; ++nt)
#pragma unroll
        for (int r = 0; r < 4; ++r)
          kq_out[(size_t)(b0 + quad * 4 + r) * 1024 + h * 256 + w * 64 + nt * 16 + l16] =
              (bf16)acc[nt][r];
    }
  }
}

// ---------------------------------------------------------------------------
// fused: per-batch chain s..c. grid 4096 x 256 thr, 4 blocks/CU.
// ---------------------------------------------------------------------------
__launch_bounds__(256, 4)
__global__ void fused_kernel(
    const float* __restrict__ x_stat, const float* __restrict__ b_stat,
    const float* __restrict__ g_nstat, const float* __restrict__ b_nstat,
    const float* __restrict__ bv, const float* __restrict__ g_mlp,
    const float* __restrict__ b_mlp, const float* __restrict__ b1,
    const float* __restrict__ b2, const float* __restrict__ bo,
    const float* __restrict__ res_scale_p,
    const float* __restrict__ h0g, const float* __restrict__ bkq_g,
    const bf16* __restrict__ Wstat_p, const bf16* __restrict__ Wv_p,
    const bf16* __restrict__ W1_p, const bf16* __restrict__ W2_p,
    const bf16* __restrict__ Wo_p, const bf16* __restrict__ kq_g,
    float* __restrict__ out_c, float* __restrict__ out_wm) {

  __shared__ bf16 buf[64 * SROW];       // 33792 B; first 64*72 doubles as xs
  __shared__ float part_s[4][64];       // LN partials; reused as zflat in P6
  __shared__ float part_ss[4][64];
  __shared__ float watt[4][64];
  __shared__ float swh[4];

  const int b = blockIdx.x;
  const int tid = threadIdx.x;
  const int w = tid >> 6, lane = tid & 63, quad = lane >> 4, l16 = lane & 15;
  const int koff = quad * 8;

  // ---- P0: stage x fp32 -> bf16 LDS (alias over buf), fully coalesced ----
  bf16* xs = buf;
  {
    const float* xb = x_stat + (size_t)b * 4096;
#pragma unroll
    for (int j = 0; j < 4; ++j) {
      int idx = j * 1024 + tid * 4;
      float4 v = *(const float4*)(xb + idx);
      bf16x4 o;
      o[0] = (bf16)v.x; o[1] = (bf16)v.y; o[2] = (bf16)v.z; o[3] = (bf16)v.w;
      *(bf16x4*)(xs + (idx >> 6) * XROW + (idx & 63)) = o;
    }
  }
  __syncthreads();

  // ---- P1: s = x @ W_stat + b_stat (swapped; K=64) + fused LN(g_nstat) ----
  {
    f32x4 acc[4][4];
    zero_acc(acc);
    const bf16* wsb = Wstat_p + (size_t)w * 2 * 2048 + lane * 8;
    bf16x8 aw[2][4];
#pragma unroll
    for (int ks = 0; ks < 2; ++ks)
#pragma unroll
      for (int dt = 0; dt < 4; ++dt)
        aw[ks][dt] = *(const bf16x8*)(wsb + ks * 2048 + dt * 512);
#pragma unroll
    for (int ks = 0; ks < 2; ++ks)
#pragma unroll
      for (int tt = 0; tt < 4; ++tt) {
        bf16x8 bfrag = *(const bf16x8*)(xs + (tt * 16 + l16) * XROW + ks * 32 + koff);
#pragma unroll
        for (int dt = 0; dt < 4; ++dt) acc[dt][tt] = MFMA_B16(aw[ks][dt], bfrag, acc[dt][tt]);
      }
    bias_stats(acc, b_stat, w, quad, l16, part_s, part_ss);
    __syncthreads();  // xs reads done + partials visible
    ln_apply_store(acc, g_nstat, b_nstat, buf, part_s, part_ss, w, quad, l16);
  }
  __syncthreads();

  // ---- P3a: logits via kq (wave w -> tokens 16w..; head = l16 < 4) ----
  {
    const bf16* kq_b = kq_g + (size_t)b * 1024;
    f32x4 accL = {0.f, 0.f, 0.f, 0.f};
#pragma unroll
    for (int ks = 0; ks < 8; ++ks) {
      bf16x8 a = *(const bf16x8*)(buf + (w * 16 + l16) * SROW + ks * 32 + koff);
      bf16x8 kf = zero8();
      if (l16 < 4) kf = *(const bf16x8*)(kq_b + l16 * 256 + ks * 32 + koff);
      accL = MFMA_B16(a, kf, accL);
    }
    float bkqv = (l16 < 4) ? bkq_g[(size_t)b * 4 + l16] : 0.f;
#pragma unroll
    for (int r = 0; r < 4; ++r) {
      float lg = (accL[r] + bkqv) * 0.125f;
      float sig = RCP(1.f + __expf(-lg));
      if (l16 < 4) watt[l16][w * 16 + quad * 4 + r] = sig;  // un-normalized
    }
  }

  // ---- P3b: v = s_ln @ Wv + bv (swapped) + fused LN(g_mlp), in-place ----
  {
    f32x4 acc[4][4];
    zero_acc(acc);
    gemm_swapped_p(buf, Wv_p, w, lane, l16, koff, acc);
    bias_stats(acc, bv, w, quad, l16, part_s, part_ss);
    __syncthreads();  // all s reads done; partials + watt(sig) visible
    {
      float v = watt[w][lane];
      float den = wave_sum(v);
      float dinv = RCP(den + 1e-6f);
      watt[w][lane] = v * dinv;
      if (lane == 0) swh[w] = den * dinv;
    }
    ln_apply_store(acc, g_mlp, b_mlp, buf, part_s, part_ss, w, quad, l16);
  }
  __syncthreads();

  // ---- w_mean output (normalized watt visible after barrier) ----
  if (tid < 64)
    out_wm[(size_t)b * 64 + tid] =
        0.25f * ((watt[0][tid] + watt[1][tid]) + (watt[2][tid] + watt[3][tid]));

  // ---- P5: t1 = gelu(t_ln@W1 + b1) (swapped), in-place ----
  {
    f32x4 acc[4][4];
    zero_acc(acc);
    gemm_swapped_p(buf, W1_p, w, lane, l16, koff, acc);
    __syncthreads();  // all t_ln reads done before overwrite
#pragma unroll
    for (int dt = 0; dt < 4; ++dt) {
      const float4 bb = *(const float4*)(b1 + w * 64 + dt * 16 + quad * 4);
#pragma unroll
      for (int tt = 0; tt < 4; ++tt) {
        float v0 = acc[dt][tt][0] + bb.x;
        float v1 = acc[dt][tt][1] + bb.y;
        float v2 = acc[dt][tt][2] + bb.z;
        float v3 = acc[dt][tt][3] + bb.w;
        bf16x4 o;
        o[0] = (bf16)(v0 * RCP(1.f + __expf(-1.702f * v0)));
        o[1] = (bf16)(v1 * RCP(1.f + __expf(-1.702f * v1)));
        o[2] = (bf16)(v2 * RCP(1.f + __expf(-1.702f * v2)));
        o[3] = (bf16)(v3 * RCP(1.f + __expf(-1.702f * v3)));
        *(bf16x4*)(buf + (tt * 16 + l16) * SROW + w * 64 + dt * 16 + quad * 4) = o;
      }
    }
  }
  __syncthreads();

  // ---- P6: vtok = t1@W2 (swapped); EXACT token contraction with watt[w];
  //      zflat -> LDS; res = zflat@Wo (M=1); c written ----
  {
    f32x4 acc[4][4];
    zero_acc(acc);
    gemm_swapped_p(buf, W2_p, w, lane, l16, koff, acc);
    // acc[dt][tt][r] = vtok_nb[m = w*64+dt*16+quad*4+r, t = tt*16+l16]
    float wt[4];
#pragma unroll
    for (int tt = 0; tt < 4; ++tt) wt[tt] = watt[w][tt * 16 + l16];
    float zr[4][4];
#pragma unroll
    for (int dt = 0; dt < 4; ++dt)
#pragma unroll
      for (int r = 0; r < 4; ++r) {
        float v = wt[0] * acc[dt][0][r] + wt[1] * acc[dt][1][r] +
                  wt[2] * acc[dt][2][r] + wt[3] * acc[dt][3][r];
        // reduce over the 16 l16 lanes (tokens) sharing this m
        v += __shfl_xor(v, 1, 64);
        v += __shfl_xor(v, 2, 64);
        v += __shfl_xor(v, 4, 64);
        v += __shfl_xor(v, 8, 64);
        zr[dt][r] = v;
      }
    // zflat[m] = zr + b2[m]*swh[w]  -> LDS (reuse part_s storage)
    float* zs = &part_s[0][0];
    if (l16 == 0) {
      float sw = swh[w];
#pragma unroll
      for (int dt = 0; dt < 4; ++dt) {
        const float4 b2v = *(const float4*)(b2 + w * 64 + dt * 16 + quad * 4);
        float4 o;
        o.x = zr[dt][0] + b2v.x * sw;
        o.y = zr[dt][1] + b2v.y * sw;
        o.z = zr[dt][2] + b2v.z * sw;
        o.w = zr[dt][3] + b2v.w * sw;
        *(float4*)(zs + w * 64 + dt * 16 + quad * 4) = o;
      }
    }
    __syncthreads();
    // M=1 GEMM: res = zflat @ Wo + bo  (A row 0 from zs, B = Wo packed)
    f32x4 a4[4];
#pragma unroll
    for (int nt = 0; nt < 4; ++nt) { f32x4 z = {0.f, 0.f, 0.f, 0.f}; a4[nt] = z; }
    const bf16* base = Wo_p + (size_t)w * 8 * 2048 + lane * 8;
#pragma unroll
    for (int ks = 0; ks < 8; ++ks) {
      bf16x8 a = zero8();
      if (l16 == 0) {
        float4 u0 = *(const float4*)(zs + ks * 32 + koff);
        float4 u1 = *(const float4*)(zs + ks * 32 + koff + 4);
        a[0] = (bf16)u0.x; a[1] = (bf16)u0.y; a[2] = (bf16)u0.z; a[3] = (bf16)u0.w;
        a[4] = (bf16)u1.x; a[5] = (bf16)u1.y; a[6] = (bf16)u1.z; a[7] = (bf16)u1.w;
      }
#pragma unroll
      for (int nt = 0; nt < 4; ++nt)
        a4[nt] = MFMA_B16(a, *(const bf16x8*)(base + ks * 2048 + nt * 512), a4[nt]);
    }
    if (quad == 0) {
      float rs = *res_scale_p;
#pragma unroll
      for (int nt = 0; nt < 4; ++nt) {
        int col = w * 64 + nt * 16 + l16;
        float res = a4[nt][0] + bo[col];
        out_c[(size_t)b * 256 + col] = h0g[(size_t)b * 256 + col] + rs * res;
      }
    }
  }
}

extern "C" void kernel_launch(void* const* d_in, const int* in_sizes, int n_in,
                              void* d_out, int out_size, void* d_ws, size_t ws_size,
                              hipStream_t stream) {
  const float* h_dyn   = (const float*)d_in[0];
  const float* x_stat  = (const float*)d_in[1];
  const float* W_dyn   = (const float*)d_in[2];
  const float* b_dyn   = (const float*)d_in[3];
  const float* W_stat  = (const float*)d_in[4];
  const float* b_stat  = (const float*)d_in[5];
  const float* g_ndyn  = (const float*)d_in[6];
  const float* b_ndyn  = (const float*)d_in[7];
  const float* g_nstat = (const float*)d_in[8];
  const float* b_nstat = (const float*)d_in[9];
  const float* Wq = (const float*)d_in[10];
  const float* bq = (const float*)d_in[11];
  const float* Wk = (const float*)d_in[12];
  const float* bk = (const float*)d_in[13];
  const float* Wv = (const float*)d_in[14];
  const float* bv = (const float*)d_in[15];
  const float* g_mlp = (const float*)d_in[16];
  const float* b_mlp = (const float*)d_in[17];
  const float* W1 = (const float*)d_in[18];
  const float* b1 = (const float*)d_in[19];
  const float* W2 = (const float*)d_in[20];
  const float* b2 = (const float*)d_in[21];
  const float* Wo = (const float*)d_in[22];
  const float* bo = (const float*)d_in[23];
  const float* rs = (const float*)d_in[24];

  bf16* ws = (bf16*)d_ws;
  float* wsf = (float*)d_ws;

  prep_kernel<<<264, 256, 0, stream>>>(W_dyn, W_stat, Wq, Wk, Wv, W1, W2, Wo, ws);

  pre_kernel<<<512, 256, 0, stream>>>(h_dyn, b_dyn, g_ndyn, b_ndyn, bq, bk,
                                      ws + WDYN_P, ws + WQ_P, ws + WK_P,
                                      wsf + H0_F, ws + KQ_BF, wsf + BKQ_F);

  float* out_c = (float*)d_out;
  float* out_wm = out_c + (size_t)4096 * 256;
  fused_kernel<<<4096, 256, 0, stream>>>(
      x_stat, b_stat, g_nstat, b_nstat, bv, g_mlp, b_mlp, b1, b2, bo, rs,
      wsf + H0_F, wsf + BKQ_F,
      ws + WSTAT_P, ws + WV_P, ws + W1_P, ws + W2_P, ws + WO_P, ws + KQ_BF,
      out_c, out_wm);
}